// Round 9
// baseline (70.613 us; speedup 1.0000x reference)
//
#include <hip/hip_runtime.h>
#include <hip/hip_fp16.h>

#define Bdim 4
#define Cdim 128
#define Hdim 96
#define Wdim 96
#define HW   (Hdim*Wdim)        // 9216
#define NOC  18                 // rot conv output channels

typedef __attribute__((ext_vector_type(8))) short bf16x8;
typedef __attribute__((ext_vector_type(4))) float f32x4;
typedef _Float16 h2 __attribute__((ext_vector_type(2)));

__device__ inline short f2bf(float f) {          // round-to-nearest-even bf16
    unsigned u = __float_as_uint(f);
    unsigned r = (u + 0x7FFFu + ((u >> 16) & 1u)) >> 16;
    return (short)r;
}

__device__ inline unsigned pkh2(float a, float b) {   // (b<<16)|a as fp16 pair
    return (unsigned)__half_as_ushort(__float2half(a)) |
           ((unsigned)__half_as_ushort(__float2half(b)) << 16);
}

// ---------------------------------------------------------------------------
// Kernel 1 (prep): x -> bf16 NHWC xnh (halo-padded) + wpk A-fragments.
// IDENTICAL to R8 (control).
// ---------------------------------------------------------------------------
__global__ __launch_bounds__(256) void prep_kernel(const float* __restrict__ x,
                                                   const float* __restrict__ rot_w,
                                                   short* __restrict__ xnh,
                                                   short* __restrict__ wpk) {
    __shared__ short ldsT[96 * 72];   // [w][c_local], stride 72
    const int bid = blockIdx.x;
    const int t   = threadIdx.x;

    if (bid < 768) {
        int b = bid / 192;
        int h = (bid / 2) % 96;
        int c0 = (bid & 1) * 64;
        const float* xs = x + ((size_t)(b * Cdim + c0) * Hdim + h) * Wdim;
#pragma unroll
        for (int i = 0; i < 24; ++i) {
            int idx = i * 256 + t;           // 0..6143 = 64c x 96w
            int w  = idx % 96;
            int ci = idx / 96;
            ldsT[w * 72 + ci] = f2bf(xs[(size_t)ci * HW + w]);
        }
        __syncthreads();
        short* dst = xnh + (((size_t)b * 98 + (h + 1)) * 98 + 1) * 128 + c0;
#pragma unroll
        for (int j = 0; j < 3; ++j) {
            int idx = j * 256 + t;           // 0..767 = 96w x 8 c-groups
            int c8 = idx % 8;
            int w  = idx / 8;
            *(bf16x8*)(dst + (size_t)w * 128 + c8 * 8) = *(const bf16x8*)&ldsT[w * 72 + c8 * 8];
        }
    } else if (bid < 776) {
        int z = bid - 768;
        int b = z / 2;
        int r = (z & 1) ? 97 : 0;
        short* base = xnh + ((size_t)b * 98 + r) * 98 * 128;
        bf16x8 zero = {0,0,0,0,0,0,0,0};
        for (int i = t; i < 1568; i += 256)      // 1568*8 = 98*128
            ((bf16x8*)base)[i] = zero;
    } else if (bid < 784) {
        int z = bid - 776;
        int b = z / 2;
        int col = (z & 1) ? 97 : 0;
        bf16x8 zero = {0,0,0,0,0,0,0,0};
        for (int i = t; i < 1536; i += 256) {    // rows 1..96 x 16 c-groups
            int r  = 1 + i / 16;
            int c8 = i % 16;
            *(bf16x8*)(xnh + (((size_t)b * 98 + r) * 98 + col) * 128 + c8 * 8) = zero;
        }
    } else {
        int f = (bid - 784) * 256 + t;           // 0..36863
        int e    = f & 7;
        int l    = (f >> 3) & 63;
        int ch   = (f >> 9) & 3;
        int tap  = (f >> 11) % 9;
        int mt   = f / 18432;
        int oc = mt * 16 + (l & 15);
        int c  = ch * 32 + (l >> 4) * 8 + e;
        float v = (oc < NOC) ? rot_w[(size_t)oc * (Cdim * 9) + c * 9 + tap] : 0.f;
        wpk[f] = f2bf(v);
    }
}

// ---------------------------------------------------------------------------
// Kernel 2: conv (bf16 MFMA implicit GEMM) with FUSED coef epilogue.
// Same as R8 except epilogue format: coefq[(b*HW+px)*9 + t] =
//   uint4{ pk_f16(q00,q01), pk_f16(q10,q11), lidx, 0 }  (contiguous per px).
// ---------------------------------------------------------------------------
__global__ __launch_bounds__(256, 2) void conv_mfma(const short* __restrict__ xnh,
                                                    const short* __restrict__ wpk,
                                                    const float* __restrict__ rot_b,
                                                    uint4* __restrict__ coefq) {
    __shared__ short wlds[36864];                // 72 KB A-fragments
    __shared__ float dsc[64 * 20];               // 5 KB per-wave D scratch
    const int tid  = threadIdx.x;
    const int lane = tid & 63;
    const int wid  = tid >> 6;
    for (int i = tid; i < 4608; i += 256)
        ((bf16x8*)wlds)[i] = ((const bf16x8*)wpk)[i];
    __syncthreads();

    const int ntile = blockIdx.x * 4 + wid;      // 0..2303
    const int b   = ntile / 576;
    const int hw0 = (ntile % 576) * 16;
    const int h   = hw0 / Wdim;
    const int w0  = hw0 % Wdim;
    const int px = lane & 15, kg = lane >> 4;

    f32x4 a00 = {0,0,0,0}, a01 = {0,0,0,0};
    f32x4 a10 = {0,0,0,0}, a11 = {0,0,0,0};
    const short* xb = xnh + (((size_t)b * 98 + h) * 98 + (w0 + px)) * 128 + kg * 8;
    const short* wl = wlds + lane * 8;

    bf16x8 Bc[4], A0c[4], A1c[4];
#pragma unroll
    for (int ch = 0; ch < 4; ++ch) {             // preload tap 0
        Bc[ch]  = *(const bf16x8*)(xb + ch * 32);
        A0c[ch] = *(const bf16x8*)(wl + ch * 512);
        A1c[ch] = *(const bf16x8*)(wl + (36 + ch) * 512);
    }

#pragma unroll
    for (int tap = 0; tap < 9; ++tap) {
        bf16x8 Bn[4], A0n[4], A1n[4];
        if (tap < 8) {
            const int di = (tap + 1) / 3, dj = (tap + 1) % 3;
            const short* xr = xb + (di * 98 + dj) * 128;
#pragma unroll
            for (int ch = 0; ch < 4; ++ch) {
                Bn[ch]  = *(const bf16x8*)(xr + ch * 32);
                A0n[ch] = *(const bf16x8*)(wl + ((tap + 1) * 4 + ch) * 512);
                A1n[ch] = *(const bf16x8*)(wl + ((9 + tap + 1) * 4 + ch) * 512);
            }
        }
        a00 = __builtin_amdgcn_mfma_f32_16x16x32_bf16(A0c[0], Bc[0], a00, 0, 0, 0);
        a10 = __builtin_amdgcn_mfma_f32_16x16x32_bf16(A1c[0], Bc[0], a10, 0, 0, 0);
        a01 = __builtin_amdgcn_mfma_f32_16x16x32_bf16(A0c[1], Bc[1], a01, 0, 0, 0);
        a11 = __builtin_amdgcn_mfma_f32_16x16x32_bf16(A1c[1], Bc[1], a11, 0, 0, 0);
        a00 = __builtin_amdgcn_mfma_f32_16x16x32_bf16(A0c[2], Bc[2], a00, 0, 0, 0);
        a10 = __builtin_amdgcn_mfma_f32_16x16x32_bf16(A1c[2], Bc[2], a10, 0, 0, 0);
        a01 = __builtin_amdgcn_mfma_f32_16x16x32_bf16(A0c[3], Bc[3], a01, 0, 0, 0);
        a11 = __builtin_amdgcn_mfma_f32_16x16x32_bf16(A1c[3], Bc[3], a11, 0, 0, 0);
        if (tap < 8) {
#pragma unroll
            for (int ch = 0; ch < 4; ++ch) { Bc[ch] = Bn[ch]; A0c[ch] = A0n[ch]; A1c[ch] = A1n[ch]; }
        }
    }
    f32x4 acc0 = a00 + a01;
    f32x4 acc1 = a10 + a11;

    // ---- fused coef epilogue (per-wave, no barrier) ----
    float* ds = dsc + (wid * 16) * 20;
    *(f32x4*)(ds + px * 20 + kg * 4) = acc0;
    if (kg == 0) {
        ds[px * 20 + 16] = acc1[0];
        ds[px * 20 + 17] = acc1[1];
    }
    __builtin_amdgcn_wave_barrier();

    const int px2 = lane & 15, tq = lane >> 4;
    if (tq < 3) {
        const float* dr = ds + px2 * 20;
        const int hwp = hw0 + px2;
#pragma unroll
        for (int k = 0; k < 3; ++k) {
            int tt = tq * 3 + k;
            int i = tt / 3, j = tt % 3;
            float ch = dr[2 * tt]     + rot_b[2 * tt]     + (0.5f + (float)i);
            float cw = dr[2 * tt + 1] + rot_b[2 * tt + 1] + (0.5f + (float)j);
            ch = fminf(fmaxf(ch, 0.f), 3.f);
            cw = fminf(fmaxf(cw, 0.f), 3.f);
            float h0f = floorf(ch), w0f = floorf(cw);
            float lh = ch - h0f, lw = cw - w0f;
            int h0 = (int)h0f, w0i = (int)w0f;
            float bh0 = 1.f - lh;
            float aw0 = 1.f - lw;
            if (h0 >= 3)  { h0 = 2;  bh0 = 0.f; }
            if (w0i >= 3) { w0i = 2; aw0 = 0.f; }
            float q00 = aw0 * bh0;
            float q01 = (1.f - aw0) * bh0;
            float q10 = aw0 * (1.f - bh0);
            float q11 = (1.f - aw0) * (1.f - bh0);
            uint4 cf;
            cf.x = pkh2(q00, q01);
            cf.y = pkh2(q10, q11);
            cf.z = (unsigned)(h0 * 3 + w0i);
            cf.w = 0u;
            coefq[((size_t)b * HW + hwp) * 9 + tt] = cf;
        }
    }
}

// ---------------------------------------------------------------------------
// Kernel 3: apply, channel-on-lanes. Block = 128 threads (c = tid), 16 px loop.
// Per (px,tap): coef wave-uniform (s_load SGPRs) + 1 ds_read_b64 fp16 quad +
// 1 coalesced ushort x-load + 2 v_dot2_f32_f16 + 1 FMA. NCHW store via LDS
// transpose for full-line writes.
// ---------------------------------------------------------------------------
__global__ __launch_bounds__(128) void apply_kernel(const short* __restrict__ xnh,
                                                    const uint4* __restrict__ coefq,
                                                    const float* __restrict__ weight,
                                                    float* __restrict__ out) {
    __shared__ uint2 wq[Cdim * 9];               // fp16 quads, 72B/channel
    __shared__ float ot[Cdim][17];               // store-transpose scratch
    const int c = threadIdx.x;                   // 0..127

    {   // stage weight table: quad(cell r,s) = {W[r][s],W[r][s+1],W[r+1][s],W[r+1][s+1]}
        const float* wb = weight + (size_t)c * 16;
        float w[16];
#pragma unroll
        for (int i = 0; i < 16; i += 4) {
            float4 v = *(const float4*)(wb + i);
            w[i] = v.x; w[i+1] = v.y; w[i+2] = v.z; w[i+3] = v.w;
        }
#pragma unroll
        for (int r = 0; r < 3; ++r)
#pragma unroll
            for (int s = 0; s < 3; ++s) {
                uint2 e;
                e.x = pkh2(w[r*4+s],   w[r*4+s+1]);
                e.y = pkh2(w[r*4+s+4], w[r*4+s+5]);
                wq[c * 9 + r * 3 + s] = e;
            }
    }
    __syncthreads();

    const int bpx = blockIdx.x * 16;             // 16 consecutive px, same row
    const int b   = bpx / HW;
    const int hw0 = bpx % HW;
    const int h   = hw0 / Wdim;
    const int w0  = hw0 % Wdim;

    const uint4* cq = coefq + ((size_t)b * HW + hw0) * 9;
    const unsigned short* xr0 =
        (const unsigned short*)xnh + (((size_t)(b * 98) + h) * 98 + w0) * 128 + c;

    float acc[16];
#pragma unroll
    for (int p = 0; p < 16; ++p) acc[p] = 0.f;

#pragma unroll
    for (int p = 0; p < 16; ++p) {
        const uint4* cp = cq + p * 9;            // wave-uniform -> s_load
        const unsigned short* xp = xr0 + p * 128;
#pragma unroll
        for (int t = 0; t < 9; ++t) {
            uint4 cf = cp[t];
            const int di = t / 3, dj = t % 3;
            uint2 g = wq[c * 9 + (int)cf.z];
            float xf = __uint_as_float(((unsigned)xp[(di * 98 + dj) * 128]) << 16);
            float s0 = __builtin_amdgcn_fdot2(__builtin_bit_cast(h2, cf.x),
                                              __builtin_bit_cast(h2, g.x), 0.f, false);
            float ws = __builtin_amdgcn_fdot2(__builtin_bit_cast(h2, cf.y),
                                              __builtin_bit_cast(h2, g.y), s0, false);
            acc[p] = fmaf(ws, xf, acc[p]);
        }
    }

    // transpose through LDS, then full-line NCHW stores (lanes along px)
#pragma unroll
    for (int p = 0; p < 16; ++p) ot[c][p] = acc[p];
    __syncthreads();

    const int px = threadIdx.x & 15;
    const int c8 = threadIdx.x >> 4;             // 0..7
    float* ob = out + (size_t)b * Cdim * HW + hw0 + px;
#pragma unroll
    for (int r = 0; r < 16; ++r) {
        int ci = c8 * 16 + r;
        ob[(size_t)ci * HW] = ot[ci][px];
    }
}

// ---------------------------------------------------------------------------
extern "C" void kernel_launch(void* const* d_in, const int* in_sizes, int n_in,
                              void* d_out, int out_size, void* d_ws, size_t ws_size,
                              hipStream_t stream) {
    const float* x      = (const float*)d_in[0];
    const float* rot_w  = (const float*)d_in[1];
    const float* rot_b  = (const float*)d_in[2];
    const float* weight = (const float*)d_in[3];
    float* out = (float*)d_out;

    char* ws = (char*)d_ws;
    const size_t xnh_bytes = (size_t)Bdim * 98 * 98 * 128 * 2;   // 9,834,496
    const size_t wpk_bytes = (size_t)2 * 9 * 4 * 64 * 8 * 2;     //    73,728

    short* xnh   = (short*)ws;
    short* wpk   = (short*)(ws + xnh_bytes);
    uint4* coefq = (uint4*)(ws + xnh_bytes + wpk_bytes);         // 5,308,416 B

    prep_kernel<<<928, 256, 0, stream>>>(x, rot_w, xnh, wpk);
    conv_mfma<<<576, 256, 0, stream>>>(xnh, wpk, rot_b, coefq);
    apply_kernel<<<2304, 128, 0, stream>>>(xnh, coefq, weight, out);
}

// Round 10
// 60.698 us; speedup vs baseline: 1.1634x; 1.1634x over previous
//
#include <hip/hip_runtime.h>
#include <hip/hip_fp16.h>

#define Bdim 4
#define Cdim 128
#define Hdim 96
#define Wdim 96
#define HW   (Hdim*Wdim)        // 9216
#define NOC  18                 // rot conv output channels

typedef __attribute__((ext_vector_type(8))) short bf16x8;
typedef __attribute__((ext_vector_type(4))) float f32x4;
typedef _Float16 h2 __attribute__((ext_vector_type(2)));

__device__ inline short f2bf(float f) {          // round-to-nearest-even bf16
    unsigned u = __float_as_uint(f);
    unsigned r = (u + 0x7FFFu + ((u >> 16) & 1u)) >> 16;
    return (short)r;
}

__device__ inline unsigned pkh2(float a, float b) {   // (b<<16)|a as fp16 pair
    return (unsigned)__half_as_ushort(__float2half(a)) |
           ((unsigned)__half_as_ushort(__float2half(b)) << 16);
}

// ---------------------------------------------------------------------------
// Kernel 1 (prep): x -> bf16 NHWC xnh (halo-padded) + wpk A-fragments.
// IDENTICAL to R9 (control).
// ---------------------------------------------------------------------------
__global__ __launch_bounds__(256) void prep_kernel(const float* __restrict__ x,
                                                   const float* __restrict__ rot_w,
                                                   short* __restrict__ xnh,
                                                   short* __restrict__ wpk) {
    __shared__ short ldsT[96 * 72];   // [w][c_local], stride 72
    const int bid = blockIdx.x;
    const int t   = threadIdx.x;

    if (bid < 768) {
        int b = bid / 192;
        int h = (bid / 2) % 96;
        int c0 = (bid & 1) * 64;
        const float* xs = x + ((size_t)(b * Cdim + c0) * Hdim + h) * Wdim;
#pragma unroll
        for (int i = 0; i < 24; ++i) {
            int idx = i * 256 + t;           // 0..6143 = 64c x 96w
            int w  = idx % 96;
            int ci = idx / 96;
            ldsT[w * 72 + ci] = f2bf(xs[(size_t)ci * HW + w]);
        }
        __syncthreads();
        short* dst = xnh + (((size_t)b * 98 + (h + 1)) * 98 + 1) * 128 + c0;
#pragma unroll
        for (int j = 0; j < 3; ++j) {
            int idx = j * 256 + t;           // 0..767 = 96w x 8 c-groups
            int c8 = idx % 8;
            int w  = idx / 8;
            *(bf16x8*)(dst + (size_t)w * 128 + c8 * 8) = *(const bf16x8*)&ldsT[w * 72 + c8 * 8];
        }
    } else if (bid < 776) {
        int z = bid - 768;
        int b = z / 2;
        int r = (z & 1) ? 97 : 0;
        short* base = xnh + ((size_t)b * 98 + r) * 98 * 128;
        bf16x8 zero = {0,0,0,0,0,0,0,0};
        for (int i = t; i < 1568; i += 256)      // 1568*8 = 98*128
            ((bf16x8*)base)[i] = zero;
    } else if (bid < 784) {
        int z = bid - 776;
        int b = z / 2;
        int col = (z & 1) ? 97 : 0;
        bf16x8 zero = {0,0,0,0,0,0,0,0};
        for (int i = t; i < 1536; i += 256) {    // rows 1..96 x 16 c-groups
            int r  = 1 + i / 16;
            int c8 = i % 16;
            *(bf16x8*)(xnh + (((size_t)b * 98 + r) * 98 + col) * 128 + c8 * 8) = zero;
        }
    } else {
        int f = (bid - 784) * 256 + t;           // 0..36863
        int e    = f & 7;
        int l    = (f >> 3) & 63;
        int ch   = (f >> 9) & 3;
        int tap  = (f >> 11) % 9;
        int mt   = f / 18432;
        int oc = mt * 16 + (l & 15);
        int c  = ch * 32 + (l >> 4) * 8 + e;
        float v = (oc < NOC) ? rot_w[(size_t)oc * (Cdim * 9) + c * 9 + tap] : 0.f;
        wpk[f] = f2bf(v);
    }
}

// ---------------------------------------------------------------------------
// Kernel 2: conv (bf16 MFMA implicit GEMM) with FUSED coef epilogue.
// IDENTICAL to R9 (control). coefq[(b*HW+px)*9 + t] =
//   uint4{ pk_f16(q00,q01), pk_f16(q10,q11), lidx, 0 }.
// ---------------------------------------------------------------------------
__global__ __launch_bounds__(256, 2) void conv_mfma(const short* __restrict__ xnh,
                                                    const short* __restrict__ wpk,
                                                    const float* __restrict__ rot_b,
                                                    uint4* __restrict__ coefq) {
    __shared__ short wlds[36864];                // 72 KB A-fragments
    __shared__ float dsc[64 * 20];               // 5 KB per-wave D scratch
    const int tid  = threadIdx.x;
    const int lane = tid & 63;
    const int wid  = tid >> 6;
    for (int i = tid; i < 4608; i += 256)
        ((bf16x8*)wlds)[i] = ((const bf16x8*)wpk)[i];
    __syncthreads();

    const int ntile = blockIdx.x * 4 + wid;      // 0..2303
    const int b   = ntile / 576;
    const int hw0 = (ntile % 576) * 16;
    const int h   = hw0 / Wdim;
    const int w0  = hw0 % Wdim;
    const int px = lane & 15, kg = lane >> 4;

    f32x4 a00 = {0,0,0,0}, a01 = {0,0,0,0};
    f32x4 a10 = {0,0,0,0}, a11 = {0,0,0,0};
    const short* xb = xnh + (((size_t)b * 98 + h) * 98 + (w0 + px)) * 128 + kg * 8;
    const short* wl = wlds + lane * 8;

    bf16x8 Bc[4], A0c[4], A1c[4];
#pragma unroll
    for (int ch = 0; ch < 4; ++ch) {             // preload tap 0
        Bc[ch]  = *(const bf16x8*)(xb + ch * 32);
        A0c[ch] = *(const bf16x8*)(wl + ch * 512);
        A1c[ch] = *(const bf16x8*)(wl + (36 + ch) * 512);
    }

#pragma unroll
    for (int tap = 0; tap < 9; ++tap) {
        bf16x8 Bn[4], A0n[4], A1n[4];
        if (tap < 8) {
            const int di = (tap + 1) / 3, dj = (tap + 1) % 3;
            const short* xr = xb + (di * 98 + dj) * 128;
#pragma unroll
            for (int ch = 0; ch < 4; ++ch) {
                Bn[ch]  = *(const bf16x8*)(xr + ch * 32);
                A0n[ch] = *(const bf16x8*)(wl + ((tap + 1) * 4 + ch) * 512);
                A1n[ch] = *(const bf16x8*)(wl + ((9 + tap + 1) * 4 + ch) * 512);
            }
        }
        a00 = __builtin_amdgcn_mfma_f32_16x16x32_bf16(A0c[0], Bc[0], a00, 0, 0, 0);
        a10 = __builtin_amdgcn_mfma_f32_16x16x32_bf16(A1c[0], Bc[0], a10, 0, 0, 0);
        a01 = __builtin_amdgcn_mfma_f32_16x16x32_bf16(A0c[1], Bc[1], a01, 0, 0, 0);
        a11 = __builtin_amdgcn_mfma_f32_16x16x32_bf16(A1c[1], Bc[1], a11, 0, 0, 0);
        a00 = __builtin_amdgcn_mfma_f32_16x16x32_bf16(A0c[2], Bc[2], a00, 0, 0, 0);
        a10 = __builtin_amdgcn_mfma_f32_16x16x32_bf16(A1c[2], Bc[2], a10, 0, 0, 0);
        a01 = __builtin_amdgcn_mfma_f32_16x16x32_bf16(A0c[3], Bc[3], a01, 0, 0, 0);
        a11 = __builtin_amdgcn_mfma_f32_16x16x32_bf16(A1c[3], Bc[3], a11, 0, 0, 0);
        if (tap < 8) {
#pragma unroll
            for (int ch = 0; ch < 4; ++ch) { Bc[ch] = Bn[ch]; A0c[ch] = A0n[ch]; A1c[ch] = A1n[ch]; }
        }
    }
    f32x4 acc0 = a00 + a01;
    f32x4 acc1 = a10 + a11;

    // ---- fused coef epilogue (per-wave, no barrier) ----
    float* ds = dsc + (wid * 16) * 20;
    *(f32x4*)(ds + px * 20 + kg * 4) = acc0;
    if (kg == 0) {
        ds[px * 20 + 16] = acc1[0];
        ds[px * 20 + 17] = acc1[1];
    }
    __builtin_amdgcn_wave_barrier();

    const int px2 = lane & 15, tq = lane >> 4;
    if (tq < 3) {
        const float* dr = ds + px2 * 20;
        const int hwp = hw0 + px2;
#pragma unroll
        for (int k = 0; k < 3; ++k) {
            int tt = tq * 3 + k;
            int i = tt / 3, j = tt % 3;
            float ch = dr[2 * tt]     + rot_b[2 * tt]     + (0.5f + (float)i);
            float cw = dr[2 * tt + 1] + rot_b[2 * tt + 1] + (0.5f + (float)j);
            ch = fminf(fmaxf(ch, 0.f), 3.f);
            cw = fminf(fmaxf(cw, 0.f), 3.f);
            float h0f = floorf(ch), w0f = floorf(cw);
            float lh = ch - h0f, lw = cw - w0f;
            int h0 = (int)h0f, w0i = (int)w0f;
            float bh0 = 1.f - lh;
            float aw0 = 1.f - lw;
            if (h0 >= 3)  { h0 = 2;  bh0 = 0.f; }
            if (w0i >= 3) { w0i = 2; aw0 = 0.f; }
            float q00 = aw0 * bh0;
            float q01 = (1.f - aw0) * bh0;
            float q10 = aw0 * (1.f - bh0);
            float q11 = (1.f - aw0) * (1.f - bh0);
            uint4 cf;
            cf.x = pkh2(q00, q01);
            cf.y = pkh2(q10, q11);
            cf.z = (unsigned)(h0 * 3 + w0i);
            cf.w = 0u;
            coefq[((size_t)b * HW + hwp) * 9 + tt] = cf;
        }
    }
}

// ---------------------------------------------------------------------------
// Kernel 3: apply. Block = 256 thr = 4 waves x 4 px; lane = channel-pair.
// x window (3 rows x 6 cols x 2ch, uint each) hoisted to registers: the 36
// (px,tap) inner iterations do ZERO VMEM — 1 ds_read_b128 table quad +
// 4 v_dot2_f32_f16 + 2 FMA. coef is wave-uniform -> readfirstlane + s_load.
// Stores via [px][c] LDS transpose (coalesced 64B runs).
// ---------------------------------------------------------------------------
__global__ __launch_bounds__(256) void apply_kernel(const short* __restrict__ xnh,
                                                    const uint4* __restrict__ coefq,
                                                    const float* __restrict__ weight,
                                                    float* __restrict__ out) {
    __shared__ uint4 wq4[9][64];     // [cell][c-pair]: {top(c0),bot(c0),top(c1),bot(c1)}
    __shared__ float ot[16][130];    // [px][c] store-transpose scratch (8320 B)
    const int tid  = threadIdx.x;
    const int lane = tid & 63;
    const int wv   = tid >> 6;       // 0..3

    // stage table: 576 entries over 256 threads
    for (int i = tid; i < 576; i += 256) {
        int e = i >> 6;              // cell 0..8
        int l = i & 63;              // c-pair
        int r = e / 3, s = e % 3;
        const float* w0p = weight + (size_t)(2 * l) * 16;
        uint4 v;
        v.x = pkh2(w0p[r * 4 + s],      w0p[r * 4 + s + 1]);
        v.y = pkh2(w0p[r * 4 + s + 4],  w0p[r * 4 + s + 5]);
        v.z = pkh2(w0p[16 + r * 4 + s],     w0p[16 + r * 4 + s + 1]);
        v.w = pkh2(w0p[16 + r * 4 + s + 4], w0p[16 + r * 4 + s + 5]);
        wq4[e][l] = v;
    }
    __syncthreads();

    const int bpx = blockIdx.x * 16;             // 16 consecutive px, same row
    const int b   = bpx / HW;
    const int hw0 = bpx % HW;
    const int h   = hw0 / Wdim;
    const int w0  = hw0 % Wdim;

    // register x window: rows h..h+2, cols (w0+4*wv)..(w0+4*wv+5), ch pair 2*lane
    const unsigned* xbase =
        (const unsigned*)(xnh + (((size_t)b * 98 + h) * 98 + (w0 + 4 * wv)) * 128) + lane;
    unsigned xw[3][6];
#pragma unroll
    for (int r = 0; r < 3; ++r)
#pragma unroll
        for (int j = 0; j < 6; ++j)
            xw[r][j] = xbase[(r * 98 + j) * 64];

    float acc0[4], acc1[4];
#pragma unroll
    for (int p = 0; p < 4; ++p) { acc0[p] = 0.f; acc1[p] = 0.f; }

    const uint4* cqb = coefq + ((size_t)b * HW + hw0) * 9;
#pragma unroll
    for (int pp = 0; pp < 4; ++pp) {
        int p = __builtin_amdgcn_readfirstlane(4 * wv + pp);   // wave-uniform -> SGPR
        const uint4* cp = cqb + p * 9;
#pragma unroll
        for (int t = 0; t < 9; ++t) {
            uint4 cf = cp[t];                    // s_load (uniform)
            uint4 g  = wq4[cf.z][lane];          // ds_read_b128, conflict-free
            unsigned xu = xw[t / 3][pp + (t % 3)];
            float x0 = __uint_as_float(xu << 16);
            float x1 = __uint_as_float(xu & 0xFFFF0000u);
            float s0 = __builtin_amdgcn_fdot2(__builtin_bit_cast(h2, cf.x),
                                              __builtin_bit_cast(h2, g.x), 0.f, false);
            s0 = __builtin_amdgcn_fdot2(__builtin_bit_cast(h2, cf.y),
                                        __builtin_bit_cast(h2, g.y), s0, false);
            float s1 = __builtin_amdgcn_fdot2(__builtin_bit_cast(h2, cf.x),
                                              __builtin_bit_cast(h2, g.z), 0.f, false);
            s1 = __builtin_amdgcn_fdot2(__builtin_bit_cast(h2, cf.y),
                                        __builtin_bit_cast(h2, g.w), s1, false);
            acc0[pp] = fmaf(s0, x0, acc0[pp]);
            acc1[pp] = fmaf(s1, x1, acc1[pp]);
        }
    }

    // transpose through LDS: write [px][c] (float2, 2-way banks = free)
#pragma unroll
    for (int pp = 0; pp < 4; ++pp)
        *(float2*)&ot[4 * wv + pp][2 * lane] = make_float2(acc0[pp], acc1[pp]);
    __syncthreads();

    const int px = tid & 15;
    const int cr = tid >> 4;                     // 0..15
    float* ob = out + (size_t)b * Cdim * HW + hw0 + px;
#pragma unroll
    for (int k = 0; k < 8; ++k) {
        int ci = cr * 8 + k;
        ob[(size_t)ci * HW] = ot[px][ci];
    }
}

// ---------------------------------------------------------------------------
extern "C" void kernel_launch(void* const* d_in, const int* in_sizes, int n_in,
                              void* d_out, int out_size, void* d_ws, size_t ws_size,
                              hipStream_t stream) {
    const float* x      = (const float*)d_in[0];
    const float* rot_w  = (const float*)d_in[1];
    const float* rot_b  = (const float*)d_in[2];
    const float* weight = (const float*)d_in[3];
    float* out = (float*)d_out;

    char* ws = (char*)d_ws;
    const size_t xnh_bytes = (size_t)Bdim * 98 * 98 * 128 * 2;   // 9,834,496
    const size_t wpk_bytes = (size_t)2 * 9 * 4 * 64 * 8 * 2;     //    73,728

    short* xnh   = (short*)ws;
    short* wpk   = (short*)(ws + xnh_bytes);
    uint4* coefq = (uint4*)(ws + xnh_bytes + wpk_bytes);         // 5,308,416 B

    prep_kernel<<<928, 256, 0, stream>>>(x, rot_w, xnh, wpk);
    conv_mfma<<<576, 256, 0, stream>>>(xnh, wpk, rot_b, coefq);
    apply_kernel<<<2304, 256, 0, stream>>>(xnh, coefq, weight, out);
}

// Round 11
// 53.377 us; speedup vs baseline: 1.3229x; 1.1371x over previous
//
#include <hip/hip_runtime.h>
#include <hip/hip_fp16.h>

#define Bdim 4
#define Cdim 128
#define Hdim 96
#define Wdim 96
#define HW   (Hdim*Wdim)        // 9216
#define NOC  18                 // rot conv output channels

typedef __attribute__((ext_vector_type(8))) short bf16x8;
typedef __attribute__((ext_vector_type(4))) float f32x4;
typedef _Float16 h2 __attribute__((ext_vector_type(2)));

__device__ inline short f2bf(float f) {          // round-to-nearest-even bf16
    unsigned u = __float_as_uint(f);
    unsigned r = (u + 0x7FFFu + ((u >> 16) & 1u)) >> 16;
    return (short)r;
}

__device__ inline unsigned pkh2(float a, float b) {   // (b<<16)|a as fp16 pair
    return (unsigned)__half_as_ushort(__float2half(a)) |
           ((unsigned)__half_as_ushort(__float2half(b)) << 16);
}

// ---------------------------------------------------------------------------
// Kernel 1 (prep): x -> bf16 NHWC xnh (halo-padded) + wpk A-fragments +
// packed fp16 weight-quad table wtab (NEW role, bid==928).
//  [0,768)    interior LDS-transpose -> xnh.
//  [768,776)  zero xnh halo rows.  [776,784) zero xnh halo cols.
//  [784,928)  repack rot_w -> wpk.  [928]    pack weight -> wtab[cell][cpair].
// ---------------------------------------------------------------------------
__global__ __launch_bounds__(256) void prep_kernel(const float* __restrict__ x,
                                                   const float* __restrict__ rot_w,
                                                   const float* __restrict__ weight,
                                                   short* __restrict__ xnh,
                                                   short* __restrict__ wpk,
                                                   uint4* __restrict__ wtab) {
    __shared__ short ldsT[96 * 72];   // [w][c_local], stride 72
    const int bid = blockIdx.x;
    const int t   = threadIdx.x;

    if (bid < 768) {
        int b = bid / 192;
        int h = (bid / 2) % 96;
        int c0 = (bid & 1) * 64;
        const float* xs = x + ((size_t)(b * Cdim + c0) * Hdim + h) * Wdim;
#pragma unroll
        for (int i = 0; i < 24; ++i) {
            int idx = i * 256 + t;           // 0..6143 = 64c x 96w
            int w  = idx % 96;
            int ci = idx / 96;
            ldsT[w * 72 + ci] = f2bf(xs[(size_t)ci * HW + w]);
        }
        __syncthreads();
        short* dst = xnh + (((size_t)b * 98 + (h + 1)) * 98 + 1) * 128 + c0;
#pragma unroll
        for (int j = 0; j < 3; ++j) {
            int idx = j * 256 + t;           // 0..767 = 96w x 8 c-groups
            int c8 = idx % 8;
            int w  = idx / 8;
            *(bf16x8*)(dst + (size_t)w * 128 + c8 * 8) = *(const bf16x8*)&ldsT[w * 72 + c8 * 8];
        }
    } else if (bid < 776) {
        int z = bid - 768;
        int b = z / 2;
        int r = (z & 1) ? 97 : 0;
        short* base = xnh + ((size_t)b * 98 + r) * 98 * 128;
        bf16x8 zero = {0,0,0,0,0,0,0,0};
        for (int i = t; i < 1568; i += 256)      // 1568*8 = 98*128
            ((bf16x8*)base)[i] = zero;
    } else if (bid < 784) {
        int z = bid - 776;
        int b = z / 2;
        int col = (z & 1) ? 97 : 0;
        bf16x8 zero = {0,0,0,0,0,0,0,0};
        for (int i = t; i < 1536; i += 256) {    // rows 1..96 x 16 c-groups
            int r  = 1 + i / 16;
            int c8 = i % 16;
            *(bf16x8*)(xnh + (((size_t)b * 98 + r) * 98 + col) * 128 + c8 * 8) = zero;
        }
    } else if (bid < 928) {
        int f = (bid - 784) * 256 + t;           // 0..36863
        int e    = f & 7;
        int l    = (f >> 3) & 63;
        int ch   = (f >> 9) & 3;
        int tap  = (f >> 11) % 9;
        int mt   = f / 18432;
        int oc = mt * 16 + (l & 15);
        int c  = ch * 32 + (l >> 4) * 8 + e;
        float v = (oc < NOC) ? rot_w[(size_t)oc * (Cdim * 9) + c * 9 + tap] : 0.f;
        wpk[f] = f2bf(v);
    } else {
        // pack weight -> wtab[e*64 + l]; scattered reads happen ONCE here.
        for (int i = t; i < 576; i += 256) {
            int e = i >> 6;              // cell 0..8
            int l = i & 63;              // c-pair
            int r = e / 3, s = e % 3;
            const float* w0p = weight + (size_t)(2 * l) * 16;
            uint4 v;
            v.x = pkh2(w0p[r * 4 + s],      w0p[r * 4 + s + 1]);
            v.y = pkh2(w0p[r * 4 + s + 4],  w0p[r * 4 + s + 5]);
            v.z = pkh2(w0p[16 + r * 4 + s],     w0p[16 + r * 4 + s + 1]);
            v.w = pkh2(w0p[16 + r * 4 + s + 4], w0p[16 + r * 4 + s + 5]);
            wtab[i] = v;
        }
    }
}

// ---------------------------------------------------------------------------
// Kernel 2: conv (bf16 MFMA implicit GEMM) with FUSED coef epilogue.
// IDENTICAL to R10 (control). coefq[(b*HW+px)*9 + t] =
//   uint4{ pk_f16(q00,q01), pk_f16(q10,q11), lidx, 0 }.
// ---------------------------------------------------------------------------
__global__ __launch_bounds__(256, 2) void conv_mfma(const short* __restrict__ xnh,
                                                    const short* __restrict__ wpk,
                                                    const float* __restrict__ rot_b,
                                                    uint4* __restrict__ coefq) {
    __shared__ short wlds[36864];                // 72 KB A-fragments
    __shared__ float dsc[64 * 20];               // 5 KB per-wave D scratch
    const int tid  = threadIdx.x;
    const int lane = tid & 63;
    const int wid  = tid >> 6;
    for (int i = tid; i < 4608; i += 256)
        ((bf16x8*)wlds)[i] = ((const bf16x8*)wpk)[i];
    __syncthreads();

    const int ntile = blockIdx.x * 4 + wid;      // 0..2303
    const int b   = ntile / 576;
    const int hw0 = (ntile % 576) * 16;
    const int h   = hw0 / Wdim;
    const int w0  = hw0 % Wdim;
    const int px = lane & 15, kg = lane >> 4;

    f32x4 a00 = {0,0,0,0}, a01 = {0,0,0,0};
    f32x4 a10 = {0,0,0,0}, a11 = {0,0,0,0};
    const short* xb = xnh + (((size_t)b * 98 + h) * 98 + (w0 + px)) * 128 + kg * 8;
    const short* wl = wlds + lane * 8;

    bf16x8 Bc[4], A0c[4], A1c[4];
#pragma unroll
    for (int ch = 0; ch < 4; ++ch) {             // preload tap 0
        Bc[ch]  = *(const bf16x8*)(xb + ch * 32);
        A0c[ch] = *(const bf16x8*)(wl + ch * 512);
        A1c[ch] = *(const bf16x8*)(wl + (36 + ch) * 512);
    }

#pragma unroll
    for (int tap = 0; tap < 9; ++tap) {
        bf16x8 Bn[4], A0n[4], A1n[4];
        if (tap < 8) {
            const int di = (tap + 1) / 3, dj = (tap + 1) % 3;
            const short* xr = xb + (di * 98 + dj) * 128;
#pragma unroll
            for (int ch = 0; ch < 4; ++ch) {
                Bn[ch]  = *(const bf16x8*)(xr + ch * 32);
                A0n[ch] = *(const bf16x8*)(wl + ((tap + 1) * 4 + ch) * 512);
                A1n[ch] = *(const bf16x8*)(wl + ((9 + tap + 1) * 4 + ch) * 512);
            }
        }
        a00 = __builtin_amdgcn_mfma_f32_16x16x32_bf16(A0c[0], Bc[0], a00, 0, 0, 0);
        a10 = __builtin_amdgcn_mfma_f32_16x16x32_bf16(A1c[0], Bc[0], a10, 0, 0, 0);
        a01 = __builtin_amdgcn_mfma_f32_16x16x32_bf16(A0c[1], Bc[1], a01, 0, 0, 0);
        a11 = __builtin_amdgcn_mfma_f32_16x16x32_bf16(A1c[1], Bc[1], a11, 0, 0, 0);
        a00 = __builtin_amdgcn_mfma_f32_16x16x32_bf16(A0c[2], Bc[2], a00, 0, 0, 0);
        a10 = __builtin_amdgcn_mfma_f32_16x16x32_bf16(A1c[2], Bc[2], a10, 0, 0, 0);
        a01 = __builtin_amdgcn_mfma_f32_16x16x32_bf16(A0c[3], Bc[3], a01, 0, 0, 0);
        a11 = __builtin_amdgcn_mfma_f32_16x16x32_bf16(A1c[3], Bc[3], a11, 0, 0, 0);
        if (tap < 8) {
#pragma unroll
            for (int ch = 0; ch < 4; ++ch) { Bc[ch] = Bn[ch]; A0c[ch] = A0n[ch]; A1c[ch] = A1n[ch]; }
        }
    }
    f32x4 acc0 = a00 + a01;
    f32x4 acc1 = a10 + a11;

    // ---- fused coef epilogue (per-wave, no barrier) ----
    float* ds = dsc + (wid * 16) * 20;
    *(f32x4*)(ds + px * 20 + kg * 4) = acc0;
    if (kg == 0) {
        ds[px * 20 + 16] = acc1[0];
        ds[px * 20 + 17] = acc1[1];
    }
    __builtin_amdgcn_wave_barrier();

    const int px2 = lane & 15, tq = lane >> 4;
    if (tq < 3) {
        const float* dr = ds + px2 * 20;
        const int hwp = hw0 + px2;
#pragma unroll
        for (int k = 0; k < 3; ++k) {
            int tt = tq * 3 + k;
            int i = tt / 3, j = tt % 3;
            float ch = dr[2 * tt]     + rot_b[2 * tt]     + (0.5f + (float)i);
            float cw = dr[2 * tt + 1] + rot_b[2 * tt + 1] + (0.5f + (float)j);
            ch = fminf(fmaxf(ch, 0.f), 3.f);
            cw = fminf(fmaxf(cw, 0.f), 3.f);
            float h0f = floorf(ch), w0f = floorf(cw);
            float lh = ch - h0f, lw = cw - w0f;
            int h0 = (int)h0f, w0i = (int)w0f;
            float bh0 = 1.f - lh;
            float aw0 = 1.f - lw;
            if (h0 >= 3)  { h0 = 2;  bh0 = 0.f; }
            if (w0i >= 3) { w0i = 2; aw0 = 0.f; }
            float q00 = aw0 * bh0;
            float q01 = (1.f - aw0) * bh0;
            float q10 = aw0 * (1.f - bh0);
            float q11 = (1.f - aw0) * (1.f - bh0);
            uint4 cf;
            cf.x = pkh2(q00, q01);
            cf.y = pkh2(q10, q11);
            cf.z = (unsigned)(h0 * 3 + w0i);
            cf.w = 0u;
            coefq[((size_t)b * HW + hwp) * 9 + tt] = cf;
        }
    }
}

// ---------------------------------------------------------------------------
// Kernel 3: apply. Block = 256 thr = 4 waves x 4 px; lane = channel-pair.
// Same as R10 EXCEPT: table staged from prepacked wtab via coalesced b128
// copies (2-3 per thread) instead of per-block scattered weight reads.
// ---------------------------------------------------------------------------
__global__ __launch_bounds__(256) void apply_kernel(const short* __restrict__ xnh,
                                                    const uint4* __restrict__ coefq,
                                                    const uint4* __restrict__ wtab,
                                                    float* __restrict__ out) {
    __shared__ uint4 wq4[9][64];     // [cell][c-pair]
    __shared__ float ot[16][130];    // [px][c] store-transpose scratch
    const int tid  = threadIdx.x;
    const int lane = tid & 63;
    const int wv   = tid >> 6;       // 0..3

    for (int i = tid; i < 576; i += 256)          // coalesced b128 copy
        ((uint4*)wq4)[i] = wtab[i];
    __syncthreads();

    const int bpx = blockIdx.x * 16;             // 16 consecutive px, same row
    const int b   = bpx / HW;
    const int hw0 = bpx % HW;
    const int h   = hw0 / Wdim;
    const int w0  = hw0 % Wdim;

    // register x window: rows h..h+2, cols (w0+4*wv)..(w0+4*wv+5), ch pair 2*lane
    const unsigned* xbase =
        (const unsigned*)(xnh + (((size_t)b * 98 + h) * 98 + (w0 + 4 * wv)) * 128) + lane;
    unsigned xw[3][6];
#pragma unroll
    for (int r = 0; r < 3; ++r)
#pragma unroll
        for (int j = 0; j < 6; ++j)
            xw[r][j] = xbase[(r * 98 + j) * 64];

    float acc0[4], acc1[4];
#pragma unroll
    for (int p = 0; p < 4; ++p) { acc0[p] = 0.f; acc1[p] = 0.f; }

    const uint4* cqb = coefq + ((size_t)b * HW + hw0) * 9;
#pragma unroll
    for (int pp = 0; pp < 4; ++pp) {
        int p = __builtin_amdgcn_readfirstlane(4 * wv + pp);   // wave-uniform -> SGPR
        const uint4* cp = cqb + p * 9;
#pragma unroll
        for (int t = 0; t < 9; ++t) {
            uint4 cf = cp[t];                    // s_load (uniform)
            uint4 g  = wq4[cf.z][lane];          // ds_read_b128, conflict-free
            unsigned xu = xw[t / 3][pp + (t % 3)];
            float x0 = __uint_as_float(xu << 16);
            float x1 = __uint_as_float(xu & 0xFFFF0000u);
            float s0 = __builtin_amdgcn_fdot2(__builtin_bit_cast(h2, cf.x),
                                              __builtin_bit_cast(h2, g.x), 0.f, false);
            s0 = __builtin_amdgcn_fdot2(__builtin_bit_cast(h2, cf.y),
                                        __builtin_bit_cast(h2, g.y), s0, false);
            float s1 = __builtin_amdgcn_fdot2(__builtin_bit_cast(h2, cf.x),
                                              __builtin_bit_cast(h2, g.z), 0.f, false);
            s1 = __builtin_amdgcn_fdot2(__builtin_bit_cast(h2, cf.y),
                                        __builtin_bit_cast(h2, g.w), s1, false);
            acc0[pp] = fmaf(s0, x0, acc0[pp]);
            acc1[pp] = fmaf(s1, x1, acc1[pp]);
        }
    }

    // transpose through LDS: write [px][c] (float2, 2-way banks = free)
#pragma unroll
    for (int pp = 0; pp < 4; ++pp)
        *(float2*)&ot[4 * wv + pp][2 * lane] = make_float2(acc0[pp], acc1[pp]);
    __syncthreads();

    const int px = tid & 15;
    const int cr = tid >> 4;                     // 0..15
    float* ob = out + (size_t)b * Cdim * HW + hw0 + px;
#pragma unroll
    for (int k = 0; k < 8; ++k) {
        int ci = cr * 8 + k;
        ob[(size_t)ci * HW] = ot[px][ci];
    }
}

// ---------------------------------------------------------------------------
extern "C" void kernel_launch(void* const* d_in, const int* in_sizes, int n_in,
                              void* d_out, int out_size, void* d_ws, size_t ws_size,
                              hipStream_t stream) {
    const float* x      = (const float*)d_in[0];
    const float* rot_w  = (const float*)d_in[1];
    const float* rot_b  = (const float*)d_in[2];
    const float* weight = (const float*)d_in[3];
    float* out = (float*)d_out;

    char* ws = (char*)d_ws;
    const size_t xnh_bytes   = (size_t)Bdim * 98 * 98 * 128 * 2;   // 9,834,496
    const size_t wpk_bytes   = (size_t)2 * 9 * 4 * 64 * 8 * 2;     //    73,728
    const size_t coefq_bytes = (size_t)Bdim * HW * 9 * 16;         // 5,308,416

    short* xnh   = (short*)ws;
    short* wpk   = (short*)(ws + xnh_bytes);
    uint4* coefq = (uint4*)(ws + xnh_bytes + wpk_bytes);
    uint4* wtab  = (uint4*)(ws + xnh_bytes + wpk_bytes + coefq_bytes);  // 9,216 B

    prep_kernel<<<929, 256, 0, stream>>>(x, rot_w, weight, xnh, wpk, wtab);
    conv_mfma<<<576, 256, 0, stream>>>(xnh, wpk, rot_b, coefq);
    apply_kernel<<<2304, 256, 0, stream>>>(xnh, coefq, wtab, out);
}

// Round 12
// 50.101 us; speedup vs baseline: 1.4094x; 1.0654x over previous
//
#include <hip/hip_runtime.h>
#include <hip/hip_fp16.h>

#define Bdim 4
#define Cdim 128
#define Hdim 96
#define Wdim 96
#define HW   (Hdim*Wdim)        // 9216
#define NOC  18                 // rot conv output channels

typedef __attribute__((ext_vector_type(8))) short bf16x8;
typedef __attribute__((ext_vector_type(4))) float f32x4;
typedef _Float16 h2 __attribute__((ext_vector_type(2)));

__device__ inline short f2bf(float f) {          // round-to-nearest-even bf16
    unsigned u = __float_as_uint(f);
    unsigned r = (u + 0x7FFFu + ((u >> 16) & 1u)) >> 16;
    return (short)r;
}

__device__ inline unsigned pkh2(float a, float b) {   // (b<<16)|a as fp16 pair
    return (unsigned)__half_as_ushort(__float2half(a)) |
           ((unsigned)__half_as_ushort(__float2half(b)) << 16);
}

// ---------------------------------------------------------------------------
// Kernel 1 (prep): x -> bf16 NHWC xnh (halo-padded) + wpk A-fragments +
// packed fp16 weight-quad table wtab. IDENTICAL to R11 (control).
// ---------------------------------------------------------------------------
__global__ __launch_bounds__(256) void prep_kernel(const float* __restrict__ x,
                                                   const float* __restrict__ rot_w,
                                                   const float* __restrict__ weight,
                                                   short* __restrict__ xnh,
                                                   short* __restrict__ wpk,
                                                   uint4* __restrict__ wtab) {
    __shared__ short ldsT[96 * 72];   // [w][c_local], stride 72
    const int bid = blockIdx.x;
    const int t   = threadIdx.x;

    if (bid < 768) {
        int b = bid / 192;
        int h = (bid / 2) % 96;
        int c0 = (bid & 1) * 64;
        const float* xs = x + ((size_t)(b * Cdim + c0) * Hdim + h) * Wdim;
#pragma unroll
        for (int i = 0; i < 24; ++i) {
            int idx = i * 256 + t;           // 0..6143 = 64c x 96w
            int w  = idx % 96;
            int ci = idx / 96;
            ldsT[w * 72 + ci] = f2bf(xs[(size_t)ci * HW + w]);
        }
        __syncthreads();
        short* dst = xnh + (((size_t)b * 98 + (h + 1)) * 98 + 1) * 128 + c0;
#pragma unroll
        for (int j = 0; j < 3; ++j) {
            int idx = j * 256 + t;           // 0..767 = 96w x 8 c-groups
            int c8 = idx % 8;
            int w  = idx / 8;
            *(bf16x8*)(dst + (size_t)w * 128 + c8 * 8) = *(const bf16x8*)&ldsT[w * 72 + c8 * 8];
        }
    } else if (bid < 776) {
        int z = bid - 768;
        int b = z / 2;
        int r = (z & 1) ? 97 : 0;
        short* base = xnh + ((size_t)b * 98 + r) * 98 * 128;
        bf16x8 zero = {0,0,0,0,0,0,0,0};
        for (int i = t; i < 1568; i += 256)      // 1568*8 = 98*128
            ((bf16x8*)base)[i] = zero;
    } else if (bid < 784) {
        int z = bid - 776;
        int b = z / 2;
        int col = (z & 1) ? 97 : 0;
        bf16x8 zero = {0,0,0,0,0,0,0,0};
        for (int i = t; i < 1536; i += 256) {    // rows 1..96 x 16 c-groups
            int r  = 1 + i / 16;
            int c8 = i % 16;
            *(bf16x8*)(xnh + (((size_t)b * 98 + r) * 98 + col) * 128 + c8 * 8) = zero;
        }
    } else if (bid < 928) {
        int f = (bid - 784) * 256 + t;           // 0..36863
        int e    = f & 7;
        int l    = (f >> 3) & 63;
        int ch   = (f >> 9) & 3;
        int tap  = (f >> 11) % 9;
        int mt   = f / 18432;
        int oc = mt * 16 + (l & 15);
        int c  = ch * 32 + (l >> 4) * 8 + e;
        float v = (oc < NOC) ? rot_w[(size_t)oc * (Cdim * 9) + c * 9 + tap] : 0.f;
        wpk[f] = f2bf(v);
    } else {
        for (int i = t; i < 576; i += 256) {
            int e = i >> 6;              // cell 0..8
            int l = i & 63;              // c-pair
            int r = e / 3, s = e % 3;
            const float* w0p = weight + (size_t)(2 * l) * 16;
            uint4 v;
            v.x = pkh2(w0p[r * 4 + s],      w0p[r * 4 + s + 1]);
            v.y = pkh2(w0p[r * 4 + s + 4],  w0p[r * 4 + s + 5]);
            v.z = pkh2(w0p[16 + r * 4 + s],     w0p[16 + r * 4 + s + 1]);
            v.w = pkh2(w0p[16 + r * 4 + s + 4], w0p[16 + r * 4 + s + 5]);
            wtab[i] = v;
        }
    }
}

// ---------------------------------------------------------------------------
// Kernel 2: conv (bf16 MFMA implicit GEMM) with FUSED coef epilogue.
// IDENTICAL to R11 (control). coefq[(b*HW+px)*9 + t] =
//   uint4{ pk_f16(q00,q01), pk_f16(q10,q11), lidx, 0 }.
// ---------------------------------------------------------------------------
__global__ __launch_bounds__(256, 2) void conv_mfma(const short* __restrict__ xnh,
                                                    const short* __restrict__ wpk,
                                                    const float* __restrict__ rot_b,
                                                    uint4* __restrict__ coefq) {
    __shared__ short wlds[36864];                // 72 KB A-fragments
    __shared__ float dsc[64 * 20];               // 5 KB per-wave D scratch
    const int tid  = threadIdx.x;
    const int lane = tid & 63;
    const int wid  = tid >> 6;
    for (int i = tid; i < 4608; i += 256)
        ((bf16x8*)wlds)[i] = ((const bf16x8*)wpk)[i];
    __syncthreads();

    const int ntile = blockIdx.x * 4 + wid;      // 0..2303
    const int b   = ntile / 576;
    const int hw0 = (ntile % 576) * 16;
    const int h   = hw0 / Wdim;
    const int w0  = hw0 % Wdim;
    const int px = lane & 15, kg = lane >> 4;

    f32x4 a00 = {0,0,0,0}, a01 = {0,0,0,0};
    f32x4 a10 = {0,0,0,0}, a11 = {0,0,0,0};
    const short* xb = xnh + (((size_t)b * 98 + h) * 98 + (w0 + px)) * 128 + kg * 8;
    const short* wl = wlds + lane * 8;

    bf16x8 Bc[4], A0c[4], A1c[4];
#pragma unroll
    for (int ch = 0; ch < 4; ++ch) {             // preload tap 0
        Bc[ch]  = *(const bf16x8*)(xb + ch * 32);
        A0c[ch] = *(const bf16x8*)(wl + ch * 512);
        A1c[ch] = *(const bf16x8*)(wl + (36 + ch) * 512);
    }

#pragma unroll
    for (int tap = 0; tap < 9; ++tap) {
        bf16x8 Bn[4], A0n[4], A1n[4];
        if (tap < 8) {
            const int di = (tap + 1) / 3, dj = (tap + 1) % 3;
            const short* xr = xb + (di * 98 + dj) * 128;
#pragma unroll
            for (int ch = 0; ch < 4; ++ch) {
                Bn[ch]  = *(const bf16x8*)(xr + ch * 32);
                A0n[ch] = *(const bf16x8*)(wl + ((tap + 1) * 4 + ch) * 512);
                A1n[ch] = *(const bf16x8*)(wl + ((9 + tap + 1) * 4 + ch) * 512);
            }
        }
        a00 = __builtin_amdgcn_mfma_f32_16x16x32_bf16(A0c[0], Bc[0], a00, 0, 0, 0);
        a10 = __builtin_amdgcn_mfma_f32_16x16x32_bf16(A1c[0], Bc[0], a10, 0, 0, 0);
        a01 = __builtin_amdgcn_mfma_f32_16x16x32_bf16(A0c[1], Bc[1], a01, 0, 0, 0);
        a11 = __builtin_amdgcn_mfma_f32_16x16x32_bf16(A1c[1], Bc[1], a11, 0, 0, 0);
        a00 = __builtin_amdgcn_mfma_f32_16x16x32_bf16(A0c[2], Bc[2], a00, 0, 0, 0);
        a10 = __builtin_amdgcn_mfma_f32_16x16x32_bf16(A1c[2], Bc[2], a10, 0, 0, 0);
        a01 = __builtin_amdgcn_mfma_f32_16x16x32_bf16(A0c[3], Bc[3], a01, 0, 0, 0);
        a11 = __builtin_amdgcn_mfma_f32_16x16x32_bf16(A1c[3], Bc[3], a11, 0, 0, 0);
        if (tap < 8) {
#pragma unroll
            for (int ch = 0; ch < 4; ++ch) { Bc[ch] = Bn[ch]; A0c[ch] = A0n[ch]; A1c[ch] = A1n[ch]; }
        }
    }
    f32x4 acc0 = a00 + a01;
    f32x4 acc1 = a10 + a11;

    // ---- fused coef epilogue (per-wave, no barrier) ----
    float* ds = dsc + (wid * 16) * 20;
    *(f32x4*)(ds + px * 20 + kg * 4) = acc0;
    if (kg == 0) {
        ds[px * 20 + 16] = acc1[0];
        ds[px * 20 + 17] = acc1[1];
    }
    __builtin_amdgcn_wave_barrier();

    const int px2 = lane & 15, tq = lane >> 4;
    if (tq < 3) {
        const float* dr = ds + px2 * 20;
        const int hwp = hw0 + px2;
#pragma unroll
        for (int k = 0; k < 3; ++k) {
            int tt = tq * 3 + k;
            int i = tt / 3, j = tt % 3;
            float ch = dr[2 * tt]     + rot_b[2 * tt]     + (0.5f + (float)i);
            float cw = dr[2 * tt + 1] + rot_b[2 * tt + 1] + (0.5f + (float)j);
            ch = fminf(fmaxf(ch, 0.f), 3.f);
            cw = fminf(fmaxf(cw, 0.f), 3.f);
            float h0f = floorf(ch), w0f = floorf(cw);
            float lh = ch - h0f, lw = cw - w0f;
            int h0 = (int)h0f, w0i = (int)w0f;
            float bh0 = 1.f - lh;
            float aw0 = 1.f - lw;
            if (h0 >= 3)  { h0 = 2;  bh0 = 0.f; }
            if (w0i >= 3) { w0i = 2; aw0 = 0.f; }
            float q00 = aw0 * bh0;
            float q01 = (1.f - aw0) * bh0;
            float q10 = aw0 * (1.f - bh0);
            float q11 = (1.f - aw0) * (1.f - bh0);
            uint4 cf;
            cf.x = pkh2(q00, q01);
            cf.y = pkh2(q10, q11);
            cf.z = (unsigned)(h0 * 3 + w0i);
            cf.w = 0u;
            coefq[((size_t)b * HW + hwp) * 9 + tt] = cf;
        }
    }
}

// ---------------------------------------------------------------------------
// Kernel 3: apply. Same as R11 EXCEPT coef access: the block's 144 coef quads
// (2304 B, block-contiguous in coefq) are staged into LDS once with a single
// coalesced round; the inner loop reads them as wave-uniform LDS broadcasts.
// No per-iteration SMEM/global -> homogeneous LDS lgkm queue, short latency.
// ---------------------------------------------------------------------------
__global__ __launch_bounds__(256) void apply_kernel(const short* __restrict__ xnh,
                                                    const uint4* __restrict__ coefq,
                                                    const uint4* __restrict__ wtab,
                                                    float* __restrict__ out) {
    __shared__ uint4 wq4[9][64];     // [cell][c-pair]
    __shared__ uint4 clds[144];      // 16 px x 9 taps coef quads (2304 B)
    __shared__ float ot[16][130];    // [px][c] store-transpose scratch
    const int tid  = threadIdx.x;
    const int lane = tid & 63;
    const int wv   = tid >> 6;       // 0..3

    for (int i = tid; i < 576; i += 256)          // coalesced b128 copy
        ((uint4*)wq4)[i] = wtab[i];
    if (tid < 144)                                // coalesced 2304B stage
        clds[tid] = coefq[(size_t)blockIdx.x * 144 + tid];
    __syncthreads();

    const int bpx = blockIdx.x * 16;             // 16 consecutive px, same row
    const int b   = bpx / HW;
    const int hw0 = bpx % HW;
    const int h   = hw0 / Wdim;
    const int w0  = hw0 % Wdim;

    // register x window: rows h..h+2, cols (w0+4*wv)..(w0+4*wv+5), ch pair 2*lane
    const unsigned* xbase =
        (const unsigned*)(xnh + (((size_t)b * 98 + h) * 98 + (w0 + 4 * wv)) * 128) + lane;
    unsigned xw[3][6];
#pragma unroll
    for (int r = 0; r < 3; ++r)
#pragma unroll
        for (int j = 0; j < 6; ++j)
            xw[r][j] = xbase[(r * 98 + j) * 64];

    float acc0[4], acc1[4];
#pragma unroll
    for (int p = 0; p < 4; ++p) { acc0[p] = 0.f; acc1[p] = 0.f; }

#pragma unroll
    for (int pp = 0; pp < 4; ++pp) {
        const uint4* cp = &clds[(4 * wv + pp) * 9];
#pragma unroll
        for (int t = 0; t < 9; ++t) {
            uint4 cf = cp[t];                    // wave-uniform LDS broadcast
            uint4 g  = wq4[cf.z][lane];          // ds_read_b128, conflict-free
            unsigned xu = xw[t / 3][pp + (t % 3)];
            float x0 = __uint_as_float(xu << 16);
            float x1 = __uint_as_float(xu & 0xFFFF0000u);
            float s0 = __builtin_amdgcn_fdot2(__builtin_bit_cast(h2, cf.x),
                                              __builtin_bit_cast(h2, g.x), 0.f, false);
            s0 = __builtin_amdgcn_fdot2(__builtin_bit_cast(h2, cf.y),
                                        __builtin_bit_cast(h2, g.y), s0, false);
            float s1 = __builtin_amdgcn_fdot2(__builtin_bit_cast(h2, cf.x),
                                              __builtin_bit_cast(h2, g.z), 0.f, false);
            s1 = __builtin_amdgcn_fdot2(__builtin_bit_cast(h2, cf.y),
                                        __builtin_bit_cast(h2, g.w), s1, false);
            acc0[pp] = fmaf(s0, x0, acc0[pp]);
            acc1[pp] = fmaf(s1, x1, acc1[pp]);
        }
    }

    // transpose through LDS: write [px][c] (float2, 2-way banks = free)
#pragma unroll
    for (int pp = 0; pp < 4; ++pp)
        *(float2*)&ot[4 * wv + pp][2 * lane] = make_float2(acc0[pp], acc1[pp]);
    __syncthreads();

    const int px = tid & 15;
    const int cr = tid >> 4;                     // 0..15
    float* ob = out + (size_t)b * Cdim * HW + hw0 + px;
#pragma unroll
    for (int k = 0; k < 8; ++k) {
        int ci = cr * 8 + k;
        ob[(size_t)ci * HW] = ot[px][ci];
    }
}

// ---------------------------------------------------------------------------
extern "C" void kernel_launch(void* const* d_in, const int* in_sizes, int n_in,
                              void* d_out, int out_size, void* d_ws, size_t ws_size,
                              hipStream_t stream) {
    const float* x      = (const float*)d_in[0];
    const float* rot_w  = (const float*)d_in[1];
    const float* rot_b  = (const float*)d_in[2];
    const float* weight = (const float*)d_in[3];
    float* out = (float*)d_out;

    char* ws = (char*)d_ws;
    const size_t xnh_bytes   = (size_t)Bdim * 98 * 98 * 128 * 2;   // 9,834,496
    const size_t wpk_bytes   = (size_t)2 * 9 * 4 * 64 * 8 * 2;     //    73,728
    const size_t coefq_bytes = (size_t)Bdim * HW * 9 * 16;         // 5,308,416

    short* xnh   = (short*)ws;
    short* wpk   = (short*)(ws + xnh_bytes);
    uint4* coefq = (uint4*)(ws + xnh_bytes + wpk_bytes);
    uint4* wtab  = (uint4*)(ws + xnh_bytes + wpk_bytes + coefq_bytes);  // 9,216 B

    prep_kernel<<<929, 256, 0, stream>>>(x, rot_w, weight, xnh, wpk, wtab);
    conv_mfma<<<576, 256, 0, stream>>>(xnh, wpk, rot_b, coefq);
    apply_kernel<<<2304, 256, 0, stream>>>(xnh, coefq, wtab, out);
}